// Round 6
// baseline (2601.306 us; speedup 1.0000x reference)
//
#include <hip/hip_runtime.h>

// ---------------------------------------------------------------------------
// MPNEncoder (chemprop D-MPNN) forward. MI355X/gfx950.
//   A=100000 atoms, B=200000 bonds, NB=6, H=256, FA=133, FB=147, M=5000, DEPTH=4
//
// Established facts:
//   - inputs fp32, output fp32; ws_size >= 358,432,768 B safe (do not exceed)
//   - sizes[-1] negative: pool uses jnp.repeat drop semantics
//   - split-bf16 MFMA (hi*hi + hi*lo + lo*hi) numerically free (absmax 1.72e10)
//   - ib-reuse (input_bond == 4096*mb0; iters 0,1 skip FB@Wib, add 4096*ib in
//     epilogue; d1 writes mb0 in place) proven exact (round 12 PASS, -100us)
//   - fragment-direct bond REGRESSED (round 11): gather duplication across
//     col-blocks -> real HBM traffic. LDS staging pays for gathered rows.
//   - round 12: 1822 us. bond slow 287us: MfmaUtil 18.6/VALU 16.9/HBM 18%/Occ
//     38 -> ~65% idle. VGPR_Count=64 + 64 AGPR acc = 128 combined regs
//     -> exactly 4 waves/SIMD. Pipeline depth 1 phase (~450cy) vs HBM gather
//     latency ~900cy -> every step stalls on the A-gather.
//   - round 13: infra flake ("container failed twice", no pytest output);
//     full audit clean (schedule trace, OOB, alignment, dbuf race) ->
//     resubmitting unchanged (round 2->3 precedent: identical resubmit ran).
//   - DESIGN UNDER TEST: 2-deep A-gather prefetch (pA/pB raw-capture register
//     sets, loop unrolled x2 -> issue-to-store distance ~2 phases) paid for by
//     2-group B-fragment processing (B live 32->16 regs; A re-read from LDS,
//     8->16 ds_read/step). Target: combined regs stay ~128, occupancy flat,
//     gather stalls halved.
//
// ws layout (total 358,432,768 B, unchanged):
//   [offsets 32 KB][matom fp32 A*256][mb0 B*256 f16][mb1 B*256 f16]
//   [wsplit tail 51.2 MB: persistent pre-split W (2.1 MB used)]
//   end-phase: aggbuf fp32 = mb0; iatom bf16 = mb1[0:51.2MB];
//              t1 bf16 = mb1[51.2:102.4MB]; hid fp32 = mb0 (after cat)
// ---------------------------------------------------------------------------

typedef _Float16 f16;
typedef f16 f16x4 __attribute__((ext_vector_type(4)));
typedef f16 f16x8 __attribute__((ext_vector_type(8)));
typedef __attribute__((ext_vector_type(8))) short bh8;    // 8 bf16 (4 VGPR)
typedef __attribute__((ext_vector_type(4))) float f32x4;  // MFMA C/D

#define MB_SCALE 0.000244140625f  /* 2^-12 */
#define MB_INV   4096.0f          /* 2^12  */
#define AGG_INV  16777216.0f      /* 2^24  */

__device__ __forceinline__ unsigned short f2bf_rne(float f) {
    unsigned u = __float_as_uint(f);
    unsigned r = (u + 0x7fffu + ((u >> 16) & 1u)) >> 16;
    return (unsigned short)r;
}
__device__ __forceinline__ float bfu2f(unsigned short u) {
    return __uint_as_float(((unsigned)u) << 16);
}
__device__ __forceinline__ f32x4 mfma16(bh8 a, bh8 b, f32x4 c) {
    return __builtin_amdgcn_mfma_f32_16x16x32_bf16(a, b, c, 0, 0, 0);
}

// ---------------------------------------------------------------------------
// Pre-split all weights once: transposed [n][k] (k contiguous), bf16 hi/lo.
//   WiaT [256][160] (k pad 133->160) | WibT [256][160] (147->160)
//   WhT  [3][256][256] | WlrT [256][768] | WoT [256][256]
// ---------------------------------------------------------------------------
__global__ __launch_bounds__(256) void wprep_kernel(
    const float* __restrict__ Wia, const float* __restrict__ Wib,
    const float* __restrict__ Wh,  const float* __restrict__ Wlr,
    const float* __restrict__ Wo,  short* __restrict__ ws)
{
    short* WiaT_hi = ws;                 // 40960
    short* WiaT_lo = ws + 40960;
    short* WibT_hi = ws + 81920;         // 40960
    short* WibT_lo = ws + 122880;
    short* WhT_hi  = ws + 163840;        // 196608
    short* WhT_lo  = ws + 360448;
    short* WlrT_hi = ws + 557056;        // 196608
    short* WlrT_lo = ws + 753664;
    short* WoT_hi  = ws + 950272;        // 65536
    short* WoT_lo  = ws + 1015808;       // ends 1081344 shorts = 2.16 MB

    int idx = blockIdx.x * 256 + threadIdx.x;
    float v; short *ph, *pl; int o;
    if (idx < 40960) {
        int n = idx / 160, k = idx - n * 160;
        v = (k < 133) ? Wia[(size_t)k * 256 + n] : 0.f;
        ph = WiaT_hi; pl = WiaT_lo; o = idx;
    } else if (idx < 81920) {
        int j = idx - 40960;
        int n = j / 160, k = j - n * 160;
        v = (k < 147) ? Wib[(size_t)k * 256 + n] : 0.f;
        ph = WibT_hi; pl = WibT_lo; o = j;
    } else if (idx < 278528) {
        int j = idx - 81920;
        int d = j >> 16, rem = j & 65535, n = rem >> 8, k = rem & 255;
        v = Wh[(size_t)d * 65536 + (size_t)k * 256 + n];
        ph = WhT_hi; pl = WhT_lo; o = j;   // layout d*65536 + n*256 + k == j
    } else if (idx < 475136) {
        int j = idx - 278528;
        int n = j / 768, k = j - n * 768;
        v = Wlr[(size_t)k * 256 + n];
        ph = WlrT_hi; pl = WlrT_lo; o = j;
    } else if (idx < 540672) {
        int j = idx - 475136;
        int n = j >> 8, k = j & 255;
        v = Wo[(size_t)k * 256 + n];
        ph = WoT_hi; pl = WoT_lo; o = j;
    } else return;
    unsigned short hb = f2bf_rne(v);
    ph[o] = (short)hb;
    pl[o] = (short)f2bf_rne(v - bfu2f(hb));
}

// ---------------------------------------------------------------------------
// Unified split-bf16 MFMA GEMM (streaming A): 128x256 tile, 512 thr, 8 waves.
// SRC 0: A = fp32 X [M,Kact] (zero-pad to KPAD)       (init GEMMs)
// SRC 1: A = [aggb f32 | matom f32 | iatom bf16], K=768 (cat GEMM)
// SRC 2: A = bf16 X [M,256] (no lo term)              (out GEMM)
// EPI 0: relu->f32  1: relu->bf16  2: relu*MB_SCALE->f16  3: raw->bf16
// EPI 4: relu(x+bias)->f32
// ---------------------------------------------------------------------------
template <int KPAD, int SRC, int EPI>
__global__ __launch_bounds__(512, 4) void mfma_gemm(
    const void* __restrict__ a0, const void* __restrict__ a1,
    const void* __restrict__ a2,
    const short* __restrict__ Bhi, const short* __restrict__ Blo,
    const float* __restrict__ bias, void* __restrict__ outv,
    int M, int Kact)
{
    __shared__ short As_hi[128 * 40];
    __shared__ short As_lo[(SRC == 2) ? 8 : 128 * 40];

    const int tid  = threadIdx.x;
    const int lane = tid & 63;
    const int w    = tid >> 6;          // 0..7
    const int wm   = (w >> 2) * 64;     // {0,64}
    const int wn   = (w & 3) * 64;      // {0,64,128,192}
    const int row0 = blockIdx.x * 128;

    const int sm = tid >> 2;            // staging row 0..127 (4 thr/row)
    const int sk = (tid & 3) * 8;       // staging k-offset 0/8/16/24
    const int fm = lane & 15;
    const int fk = (lane >> 4) * 8;

    int grow = row0 + sm; if (grow > M - 1) grow = M - 1;

    f32x4 acc[4][4];
#pragma unroll
    for (int i = 0; i < 4; ++i)
#pragma unroll
        for (int j = 0; j < 4; ++j) {
            f32x4 z = {0.f, 0.f, 0.f, 0.f};
            acc[i][j] = z;
        }

    for (int k0 = 0; k0 < KPAD; k0 += 32) {
        __syncthreads();
        // ---- stage A tile (pre-split), 8 elems/thread ----
        int base = sm * 40 + sk;
        if (SRC == 0) {
            const float* xrow = (const float*)a0 + (size_t)grow * Kact;
            bh8 h0, l0;
#pragma unroll
            for (int j = 0; j < 8; ++j) {
                int kc = k0 + sk + j;
                float v = (kc < Kact) ? xrow[kc] : 0.f;
                unsigned short hb = f2bf_rne(v);
                h0[j] = (short)hb; l0[j] = (short)f2bf_rne(v - bfu2f(hb));
            }
            *(bh8*)&As_hi[base] = h0;
            *(bh8*)&As_lo[base] = l0;
        } else if (SRC == 1) {
            if (k0 < 512) {
                const float* src = (k0 < 256) ? (const float*)a0 : (const float*)a1;
                int kl = k0 & 255;
                const float4* p = (const float4*)(src + (size_t)grow * 256 + kl + sk);
                float va[8];
#pragma unroll
                for (int q = 0; q < 2; ++q) {
                    float4 f = p[q];
                    va[q * 4 + 0] = f.x; va[q * 4 + 1] = f.y;
                    va[q * 4 + 2] = f.z; va[q * 4 + 3] = f.w;
                }
                bh8 h0, l0;
#pragma unroll
                for (int j = 0; j < 8; ++j) {
                    unsigned short hb = f2bf_rne(va[j]);
                    h0[j] = (short)hb; l0[j] = (short)f2bf_rne(va[j] - bfu2f(hb));
                }
                *(bh8*)&As_hi[base] = h0;
                *(bh8*)&As_lo[base] = l0;
            } else {
                const short* ia = (const short*)a2 + (size_t)grow * 256 + (k0 - 512) + sk;
                bh8 z;
#pragma unroll
                for (int j = 0; j < 8; ++j) z[j] = 0;
                *(bh8*)&As_hi[base] = *(const bh8*)ia;
                *(bh8*)&As_lo[base] = z;
            }
        } else {
            const short* xr = (const short*)a0 + (size_t)grow * 256 + k0 + sk;
            *(bh8*)&As_hi[base] = *(const bh8*)xr;
        }
        __syncthreads();

        // ---- B fragments from pre-split global (L2-resident) ----
        bh8 bhf[4], blf[4];
#pragma unroll
        for (int nt = 0; nt < 4; ++nt) {
            int n = wn + nt * 16 + fm;
            size_t off = (size_t)n * KPAD + k0 + fk;
            bhf[nt] = *(const bh8*)(Bhi + off);
            blf[nt] = *(const bh8*)(Blo + off);
        }
#pragma unroll
        for (int mt = 0; mt < 4; ++mt) {
            int abase = (wm + mt * 16 + fm) * 40 + fk;
            bh8 ah = *(const bh8*)&As_hi[abase];
#pragma unroll
            for (int nt = 0; nt < 4; ++nt) {
                acc[mt][nt] = mfma16(ah, bhf[nt], acc[mt][nt]);
                acc[mt][nt] = mfma16(ah, blf[nt], acc[mt][nt]);
            }
            if (SRC != 2) {
                bh8 al = *(const bh8*)&As_lo[abase];
#pragma unroll
                for (int nt = 0; nt < 4; ++nt)
                    acc[mt][nt] = mfma16(al, bhf[nt], acc[mt][nt]);
            }
        }
    }

    // ---- epilogue (C layout: col=lane&15, row=(lane>>4)*4+r) ----
#pragma unroll
    for (int mt = 0; mt < 4; ++mt) {
        int rbase = row0 + wm + mt * 16 + (lane >> 4) * 4;
#pragma unroll
        for (int nt = 0; nt < 4; ++nt) {
            int col = wn + nt * 16 + fm;
            float bc = (EPI == 4) ? bias[col] : 0.f;
#pragma unroll
            for (int r = 0; r < 4; ++r) {
                int row = rbase + r;
                if (row < M) {
                    size_t o = (size_t)row * 256 + col;
                    float v = acc[mt][nt][r];
                    if (EPI == 0)      ((float*)outv)[o] = fmaxf(v, 0.f);
                    else if (EPI == 1) ((unsigned short*)outv)[o] = f2bf_rne(fmaxf(v, 0.f));
                    else if (EPI == 2) ((f16*)outv)[o] = (f16)(fmaxf(v, 0.f) * MB_SCALE);
                    else if (EPI == 3) ((unsigned short*)outv)[o] = f2bf_rne(v);
                    else               ((float*)outv)[o] = fmaxf(v + bc, 0.f);
                }
            }
        }
    }
}

// ---------------------------------------------------------------------------
// Bond update via split-bf16 MFMA, 2-deep gather pipeline:
//   WITH_FB=1: mb_new = relu( relu(FB@Wib) + (matom[b2a] - 4096*mb[b2revb])@Wh ) * 2^-12
//   WITH_FB=0: mb_new = relu( 4096*ib     + (matom[b2a] - 4096*mb[b2revb])@Wh ) * 2^-12
// 128x256 tile, 512 threads, dbuf LDS, 1 barrier/step. Virtual k-steps:
// s=0..4 phase1 (K=160, Wib; WITH_FB only), s=5..12 phase2 (K=256, Wh).
// Pipeline: two RAW-capture register sets pA/pB, loop unrolled x2 -> each
// gather has ~2 compute phases from issue to LDS-store. B-fragments processed
// in 2 groups of 2 (live 16 regs, A re-read from LDS) to keep combined
// regs ~128 (4 waves/SIMD). ib/mb_new may ALIAS (d1 in-place): no __restrict__.
// ---------------------------------------------------------------------------
struct Pref { float4 a0, a1; f16x4 r0, r1; };

template <bool WITH_FB>
__global__ __launch_bounds__(512, 4) void bond_mfma_kernel(
    const float* __restrict__ FB,
    const short* __restrict__ WibT_hi, const short* __restrict__ WibT_lo,
    const short* __restrict__ WhT_hi,  const short* __restrict__ WhT_lo,
    const float* __restrict__ matom, const f16* __restrict__ mb_old,
    const f16* ib,
    const int* __restrict__ b2a, const int* __restrict__ b2revb,
    f16* mb_new, int M)
{
    __shared__ short As[2][2][128 * 40];   // [buf][hi|lo]

    const int tid  = threadIdx.x;
    const int lane = tid & 63;
    const int w    = tid >> 6;
    const int wm   = (w >> 2) * 64;
    const int wn   = (w & 3) * 64;
    const int row0 = blockIdx.x * 128;

    const int sm = tid >> 2;            // 0..127
    const int sk = (tid & 3) * 8;       // 0/8/16/24

    int grow = row0 + sm; if (grow > M - 1) grow = M - 1;
    const float* frow = FB + (size_t)grow * 147;
    const float* arow = matom + (size_t)b2a[grow] * 256;
    const f16*   rrow = mb_old + (size_t)b2revb[grow] * 256;

    const int fm = lane & 15;
    const int fk = (lane >> 4) * 8;

    f32x4 acc[4][4];
#pragma unroll
    for (int i = 0; i < 4; ++i)
#pragma unroll
        for (int j = 0; j < 4; ++j) {
            f32x4 z = {0.f, 0.f, 0.f, 0.f};
            acc[i][j] = z;
        }

    // RAW capture: no arithmetic on loaded values until store time, so the
    // compiler can keep the loads in flight across the whole pipeline span.
    auto loadv = [&](Pref& p, int s) {
        if (WITH_FB && s < 5) {         // phase 1: stream FB row (147 pad 160)
            int kb = s * 32 + sk;
            float t[8];
#pragma unroll
            for (int j = 0; j < 8; ++j) {
                int kc = kb + j;
                t[j] = (kc < 147) ? frow[kc] : 0.f;
            }
            p.a0 = make_float4(t[0], t[1], t[2], t[3]);
            p.a1 = make_float4(t[4], t[5], t[6], t[7]);
        } else {                        // phase 2: gathered matom / rev rows
            int kb = (s - 5) * 32 + sk;
            const float4* ap = (const float4*)(arow + kb);
            const f16x4*  rp = (const f16x4*)(rrow + kb);
            p.a0 = ap[0]; p.a1 = ap[1];
            p.r0 = rp[0]; p.r1 = rp[1];
        }
    };
    auto storev = [&](const Pref& p, int s, int buf) {
        float va[8];
        if (WITH_FB && s < 5) {
            va[0] = p.a0.x; va[1] = p.a0.y; va[2] = p.a0.z; va[3] = p.a0.w;
            va[4] = p.a1.x; va[5] = p.a1.y; va[6] = p.a1.z; va[7] = p.a1.w;
        } else {
            va[0] = fmaf(-MB_INV, (float)p.r0[0], p.a0.x);
            va[1] = fmaf(-MB_INV, (float)p.r0[1], p.a0.y);
            va[2] = fmaf(-MB_INV, (float)p.r0[2], p.a0.z);
            va[3] = fmaf(-MB_INV, (float)p.r0[3], p.a0.w);
            va[4] = fmaf(-MB_INV, (float)p.r1[0], p.a1.x);
            va[5] = fmaf(-MB_INV, (float)p.r1[1], p.a1.y);
            va[6] = fmaf(-MB_INV, (float)p.r1[2], p.a1.z);
            va[7] = fmaf(-MB_INV, (float)p.r1[3], p.a1.w);
        }
        bh8 h, l;
#pragma unroll
        for (int j = 0; j < 8; ++j) {
            unsigned short hb = f2bf_rne(va[j]);
            h[j] = (short)hb;
            l[j] = (short)f2bf_rne(va[j] - bfu2f(hb));
        }
        int base = sm * 40 + sk;
        *(bh8*)&As[buf][0][base] = h;
        *(bh8*)&As[buf][1][base] = l;
    };
    // B in 2 groups of 2 cols (live 16 regs), A re-read from LDS per group.
    auto compute = [&](int buf, int s) {
        const short *Bh, *Bl; int ldb, k0;
        if (WITH_FB && s < 5) { Bh = WibT_hi; Bl = WibT_lo; ldb = 160; k0 = s * 32; }
        else                  { Bh = WhT_hi;  Bl = WhT_lo;  ldb = 256; k0 = (s - 5) * 32; }
#pragma unroll
        for (int g = 0; g < 2; ++g) {
            const int nt0 = g * 2, nt1 = g * 2 + 1;
            size_t o0 = (size_t)(wn + nt0 * 16 + fm) * ldb + k0 + fk;
            size_t o1 = (size_t)(wn + nt1 * 16 + fm) * ldb + k0 + fk;
            bh8 b0h = *(const bh8*)(Bh + o0);
            bh8 b0l = *(const bh8*)(Bl + o0);
            bh8 b1h = *(const bh8*)(Bh + o1);
            bh8 b1l = *(const bh8*)(Bl + o1);
#pragma unroll
            for (int mt = 0; mt < 4; ++mt) {
                int abase = (wm + mt * 16 + fm) * 40 + fk;
                bh8 ah = *(const bh8*)&As[buf][0][abase];
                bh8 al = *(const bh8*)&As[buf][1][abase];
                acc[mt][nt0] = mfma16(ah, b0h, acc[mt][nt0]);
                acc[mt][nt0] = mfma16(ah, b0l, acc[mt][nt0]);
                acc[mt][nt0] = mfma16(al, b0h, acc[mt][nt0]);
                acc[mt][nt1] = mfma16(ah, b1h, acc[mt][nt1]);
                acc[mt][nt1] = mfma16(ah, b1l, acc[mt][nt1]);
                acc[mt][nt1] = mfma16(al, b1h, acc[mt][nt1]);
            }
        }
    };
    auto relu_acc = [&]() {
#pragma unroll
        for (int i = 0; i < 4; ++i)
#pragma unroll
            for (int j = 0; j < 4; ++j)
#pragma unroll
                for (int r = 0; r < 4; ++r)
                    acc[i][j][r] = fmaxf(acc[i][j][r], 0.f);
    };

    const int S0 = WITH_FB ? 0 : 5;
    Pref pA, pB;

    // prologue: buf0 = step S0; pA = step S0+1 (in flight)
    loadv(pA, S0);
    storev(pA, S0, 0);
    loadv(pA, S0 + 1);
    __syncthreads();

    int cur = 0;
    for (int s = S0; s <= 12; s += 2) {
        // pA holds s+1; issue s+2 into pB
        if (s + 2 <= 12) loadv(pB, s + 2);
        compute(cur, s);
        if (WITH_FB && s == 4) relu_acc();
        if (s < 12) storev(pA, s + 1, cur ^ 1);
        __syncthreads();
        cur ^= 1;
        if (s + 1 > 12) break;
        // pB holds s+2; issue s+3 into pA
        if (s + 3 <= 12) loadv(pA, s + 3);
        compute(cur, s + 1);
        if (s + 1 < 12) storev(pB, s + 2, cur ^ 1);
        __syncthreads();
        cur ^= 1;
    }

#pragma unroll
    for (int mt = 0; mt < 4; ++mt) {
        int rbase = row0 + wm + mt * 16 + (lane >> 4) * 4;
#pragma unroll
        for (int nt = 0; nt < 4; ++nt) {
            int col = wn + nt * 16 + fm;
#pragma unroll
            for (int r = 0; r < 4; ++r) {
                int row = rbase + r;
                if (row < M) {
                    size_t o = (size_t)row * 256 + col;
                    float v = acc[mt][nt][r];
                    if (!WITH_FB) v = fmaf(MB_INV, (float)ib[o], v);
                    mb_new[o] = (f16)(fmaxf(v, 0.f) * MB_SCALE);
                }
            }
        }
    }
}

// agg = sum_j(mb[a2b[a,j]]) * max_j(mb[a2b[a,j]]) per channel, true scale.
// 4 atoms/block, 64 lanes/atom, f16x4 (8B/lane) gather loads.
__global__ __launch_bounds__(256) void agg_kernel(
    const f16* __restrict__ mb, const int* __restrict__ a2b,
    float* __restrict__ matom, float* __restrict__ agg_out, int A)
{
    const int a    = blockIdx.x * 4 + (threadIdx.x >> 6);
    const int lane = threadIdx.x & 63;
    if (a >= A) return;
    const int* nb = a2b + (size_t)a * 6;

    f16x4 v0 = *(const f16x4*)(mb + (size_t)nb[0] * 256 + lane * 4);
    float s0 = (float)v0[0], s1 = (float)v0[1], s2 = (float)v0[2], s3 = (float)v0[3];
    float m0 = s0, m1 = s1, m2 = s2, m3 = s3;
#pragma unroll
    for (int j = 1; j < 6; ++j) {
        f16x4 v = *(const f16x4*)(mb + (size_t)nb[j] * 256 + lane * 4);
        float f0 = (float)v[0], f1 = (float)v[1], f2 = (float)v[2], f3 = (float)v[3];
        s0 += f0; s1 += f1; s2 += f2; s3 += f3;
        m0 = fmaxf(m0, f0); m1 = fmaxf(m1, f1);
        m2 = fmaxf(m2, f2); m3 = fmaxf(m3, f3);
    }
    size_t o = (size_t)a * 256 + lane * 4;
    if (agg_out) {
        float4 g = { AGG_INV * s0 * m0, AGG_INV * s1 * m1,
                     AGG_INV * s2 * m2, AGG_INV * s3 * m3 };
        *(float4*)(agg_out + o) = g;
    } else {
        float4 m = *(const float4*)(matom + o);
        m.x += AGG_INV * s0 * m0; m.y += AGG_INV * s1 * m1;
        m.z += AGG_INV * s2 * m2; m.w += AGG_INV * s3 * m3;
        *(float4*)(matom + o) = m;
    }
}

// Exclusive prefix sum of sizes -> offsets (one block, M=5000). Raw, unclipped.
__global__ __launch_bounds__(256) void scan_kernel(
    const int* __restrict__ sizes, int* __restrict__ offsets, int M)
{
    __shared__ int part[256];
    const int t = threadIdx.x;
    const int chunk = (M + 255) / 256;
    int begin = t * chunk;
    int end = begin + chunk; if (end > M) end = M;
    int s = 0;
    for (int i = begin; i < end && i < M; ++i) s += sizes[i];
    part[t] = s;
    __syncthreads();
    for (int off = 1; off < 256; off <<= 1) {
        int v = (t >= off) ? part[t - off] : 0;
        __syncthreads();
        part[t] += v;
        __syncthreads();
    }
    int run = part[t] - s;
    for (int i = begin; i < end && i < M; ++i) { offsets[i] = run; run += sizes[i]; }
}

// Per-molecule mean pooling with jnp.repeat(total_repeat_length=A) DROP
// semantics (sizes[M-1] may be negative).
__global__ __launch_bounds__(256) void pool_kernel(
    const float* __restrict__ hid, const int* __restrict__ offsets,
    const int* __restrict__ sizes, float* __restrict__ out, int M, int A)
{
    const int m = blockIdx.x;
    const int h = threadIdx.x;
    int e = offsets[m];
    int sz = sizes[m];
    int start = e < A ? e : A;          if (start < 0) start = 0;
    int stop  = e + sz; if (stop > A) stop = A; if (stop < 0) stop = 0;
    float s = 0.f;
    for (int i = start; i < stop; ++i)
        s += hid[(size_t)i * 256 + h];
    out[(size_t)m * 256 + h] = s / (float)sz;
}

extern "C" void kernel_launch(void* const* d_in, const int* in_sizes, int n_in,
                              void* d_out, int out_size, void* d_ws, size_t ws_size,
                              hipStream_t stream)
{
    const float* f_atoms = (const float*)d_in[0];
    const float* f_bonds = (const float*)d_in[1];
    const float* W_ia    = (const float*)d_in[2];
    const float* W_ib    = (const float*)d_in[3];
    const float* W_h     = (const float*)d_in[4];
    const float* W_o     = (const float*)d_in[5];
    const float* b_o     = (const float*)d_in[6];
    const float* W_lr    = (const float*)d_in[7];
    const int*   a2b     = (const int*)d_in[8];
    const int*   b2a     = (const int*)d_in[9];
    const int*   b2revb  = (const int*)d_in[10];
    const int*   sizes   = (const int*)d_in[11];
    float* out = (float*)d_out;   // fp32 [5000,256]

    const int An = 100000, Bn = 200000, Mm = 5000;
    const size_t ABYTES = (size_t)An * 256 * 4;   // 102,400,000
    const size_t BBYTES = (size_t)Bn * 256 * 2;   // 102,400,000 (fp16)

    int*   offsets = (int*)d_ws;                                  // 32 KB
    float* matom   = (float*)((char*)d_ws + 32768);               // fp32 [A,256]
    f16*   mb0     = (f16*)((char*)matom + ABYTES);
    f16*   mb1     = (f16*)((char*)mb0 + BBYTES);
    short* wsplit  = (short*)((char*)mb1 + BBYTES);               // 51.2 MB tail
    // total footprint unchanged: 358,432,768 B (proven safe)

    short* WiaT_hi = wsplit;
    short* WiaT_lo = wsplit + 40960;
    short* WibT_hi = wsplit + 81920;
    short* WibT_lo = wsplit + 122880;
    short* WhT_hi  = wsplit + 163840;
    short* WhT_lo  = wsplit + 360448;
    short* WlrT_hi = wsplit + 557056;
    short* WlrT_lo = wsplit + 753664;
    short* WoT_hi  = wsplit + 950272;
    short* WoT_lo  = wsplit + 1015808;

    dim3 blk(256);
    dim3 blk512(512);
    dim3 gA((An + 127) / 128, 1);    // 782
    dim3 gB((Bn + 127) / 128, 1);    // 1563

    wprep_kernel<<<2112, blk, 0, stream>>>(W_ia, W_ib, W_h, W_lr, W_o, wsplit);

    // input projections (split-MFMA)
    mfma_gemm<160, 0, 0><<<gA, blk512, 0, stream>>>(
        f_atoms, nullptr, nullptr, WiaT_hi, WiaT_lo, nullptr, matom, An, 133);
    mfma_gemm<160, 0, 2><<<gB, blk512, 0, stream>>>(
        f_bonds, nullptr, nullptr, WibT_hi, WibT_lo, nullptr, mb0, Bn, 147);

    // message passing (3 iterations); ib == initial mb0, reused by iters 0,1
    // d0: agg(mb0); fast(old=mb0, ib=mb0) -> mb1
    agg_kernel<<<(An + 3) / 4, blk, 0, stream>>>(mb0, a2b, matom, (float*)nullptr, An);
    bond_mfma_kernel<false><<<gB, blk512, 0, stream>>>(
        f_bonds, WibT_hi, WibT_lo, WhT_hi, WhT_lo,
        matom, mb0, mb0, b2a, b2revb, mb1, Bn);
    // d1: agg(mb1); fast(old=mb1, ib=mb0) -> mb0 IN-PLACE over ib (race-free:
    //     each thread reads ib[o] then writes mb_new[o] at the same o; gather
    //     source is mb1)
    agg_kernel<<<(An + 3) / 4, blk, 0, stream>>>(mb1, a2b, matom, (float*)nullptr, An);
    bond_mfma_kernel<false><<<gB, blk512, 0, stream>>>(
        f_bonds, WibT_hi, WibT_lo, WhT_hi + 65536, WhT_lo + 65536,
        matom, mb1, mb0, b2a, b2revb, mb0, Bn);
    // d2: agg(mb0); slow (recompute FB@Wib; ib destroyed) -> mb1
    agg_kernel<<<(An + 3) / 4, blk, 0, stream>>>(mb0, a2b, matom, (float*)nullptr, An);
    bond_mfma_kernel<true><<<gB, blk512, 0, stream>>>(
        f_bonds, WibT_hi, WibT_lo, WhT_hi + 131072, WhT_lo + 131072,
        matom, mb0, nullptr, b2a, b2revb, mb1, Bn);
    // final message_bond = mb1 (same as before)

    float* aggbuf = (float*)mb0;                       // fp32 [A,256]
    agg_kernel<<<(An + 3) / 4, blk, 0, stream>>>(mb1, a2b, matom, aggbuf, An);

    // iatom bf16 -> first half of (now dead) mb1; t1 bf16 -> second half
    unsigned short* iatom = (unsigned short*)mb1;
    unsigned short* t1    = (unsigned short*)((char*)mb1 + 51200000);
    mfma_gemm<160, 0, 1><<<gA, blk512, 0, stream>>>(
        f_atoms, nullptr, nullptr, WiaT_hi, WiaT_lo, nullptr, iatom, An, 133);

    mfma_gemm<768, 1, 3><<<gA, blk512, 0, stream>>>(
        aggbuf, matom, iatom, WlrT_hi, WlrT_lo, nullptr, t1, An, 768);

    float* hid = (float*)mb0;                          // aggbuf dead after cat
    mfma_gemm<256, 2, 4><<<gA, blk512, 0, stream>>>(
        t1, nullptr, nullptr, WoT_hi, WoT_lo, b_o, hid, An, 256);

    scan_kernel<<<1, 256, 0, stream>>>(sizes, offsets, Mm);
    pool_kernel<<<Mm, blk, 0, stream>>>(hid, offsets, sizes, out, Mm, An);
}

// Round 8
// 2151.040 us; speedup vs baseline: 1.2093x; 1.2093x over previous
//
#include <hip/hip_runtime.h>

// ---------------------------------------------------------------------------
// MPNEncoder (chemprop D-MPNN) forward. MI355X/gfx950.
//   A=100000 atoms, B=200000 bonds, NB=6, H=256, FA=133, FB=147, M=5000, DEPTH=4
//
// Established facts:
//   - inputs fp32, output fp32; ws_size >= 358,432,768 B safe (do not exceed)
//   - sizes[-1] negative: pool uses jnp.repeat drop semantics
//   - split-bf16 MFMA (hi*hi + hi*lo + lo*hi) numerically free (absmax 1.72e10)
//   - ib-reuse (iters 0,1 skip FB@Wib, add 4096*ib in epilogue; d1 in-place)
//     proven exact (PASS, -100us)
//   - fragment-direct bond REGRESSED (gather dup across col-blocks -> HBM)
//   - round 14 (2-deep via Pref structs + lambdas): SPILLED to scratch.
//     WRITE 150MB->1.26GB, bond 287->668us.
//   - round 12 baseline 1822us: bond slow 287 / fast ~238, MfmaUtil 18.6,
//     VALU 16.9, HBM 18%, Occ 38 (4 waves/SIMD, 64 VGPR + 64 AGPR) ->
//     ~65% idle: every k-step stalls on the 1-phase-covered A-gather.
//   - round 15: "container failed twice" infra flake. Pattern established:
//     fresh submissions flake on the 160MB input push (round-3 timing shows
//     push_in_npz_s=722s); identical resubmits run with preloaded data.
//     Kernel audit clean -> RESUBMITTING BYTE-IDENTICAL.
//   - DESIGN UNDER TEST: 2-deep gather pipeline, SPILL-PROOFED:
//     * fully static unroll (13 steps, compile-time buf/parity/phase)
//     * raw prefetch in named register sets (x*/y*), macros on scalars,
//       no structs/lambdas/arrays
//     * 2-group B processing (B live 32->16) pays for the 2nd raw set:
//       ~124 combined regs <= 128, occupancy flat
//     * LDS stride 40->44 (bank-conflict fix, 7.8M -> ~free)
//     Tripwire: if WRITE_SIZE balloons again -> spill -> revert next round.
//
// ws layout (total 358,432,768 B, unchanged):
//   [offsets 32 KB][matom fp32 A*256][mb0 B*256 f16][mb1 B*256 f16]
//   [wsplit tail 51.2 MB: persistent pre-split W (2.1 MB used)]
//   end-phase: aggbuf fp32 = mb0; iatom bf16 = mb1[0:51.2MB];
//              t1 bf16 = mb1[51.2:102.4MB]; hid fp32 = mb0 (after cat)
// ---------------------------------------------------------------------------

typedef _Float16 f16;
typedef f16 f16x4 __attribute__((ext_vector_type(4)));
typedef f16 f16x8 __attribute__((ext_vector_type(8)));
typedef __attribute__((ext_vector_type(8))) short bh8;    // 8 bf16 (4 VGPR)
typedef __attribute__((ext_vector_type(4))) float f32x4;  // MFMA C/D

#define MB_SCALE 0.000244140625f  /* 2^-12 */
#define MB_INV   4096.0f          /* 2^12  */
#define AGG_INV  16777216.0f      /* 2^24  */

__device__ __forceinline__ unsigned short f2bf_rne(float f) {
    unsigned u = __float_as_uint(f);
    unsigned r = (u + 0x7fffu + ((u >> 16) & 1u)) >> 16;
    return (unsigned short)r;
}
__device__ __forceinline__ float bfu2f(unsigned short u) {
    return __uint_as_float(((unsigned)u) << 16);
}
__device__ __forceinline__ f32x4 mfma16(bh8 a, bh8 b, f32x4 c) {
    return __builtin_amdgcn_mfma_f32_16x16x32_bf16(a, b, c, 0, 0, 0);
}

// ---------------------------------------------------------------------------
// Pre-split all weights once: transposed [n][k] (k contiguous), bf16 hi/lo.
//   WiaT [256][160] (k pad 133->160) | WibT [256][160] (147->160)
//   WhT  [3][256][256] | WlrT [256][768] | WoT [256][256]
// ---------------------------------------------------------------------------
__global__ __launch_bounds__(256) void wprep_kernel(
    const float* __restrict__ Wia, const float* __restrict__ Wib,
    const float* __restrict__ Wh,  const float* __restrict__ Wlr,
    const float* __restrict__ Wo,  short* __restrict__ ws)
{
    short* WiaT_hi = ws;                 // 40960
    short* WiaT_lo = ws + 40960;
    short* WibT_hi = ws + 81920;         // 40960
    short* WibT_lo = ws + 122880;
    short* WhT_hi  = ws + 163840;        // 196608
    short* WhT_lo  = ws + 360448;
    short* WlrT_hi = ws + 557056;        // 196608
    short* WlrT_lo = ws + 753664;
    short* WoT_hi  = ws + 950272;        // 65536
    short* WoT_lo  = ws + 1015808;       // ends 1081344 shorts = 2.16 MB

    int idx = blockIdx.x * 256 + threadIdx.x;
    float v; short *ph, *pl; int o;
    if (idx < 40960) {
        int n = idx / 160, k = idx - n * 160;
        v = (k < 133) ? Wia[(size_t)k * 256 + n] : 0.f;
        ph = WiaT_hi; pl = WiaT_lo; o = idx;
    } else if (idx < 81920) {
        int j = idx - 40960;
        int n = j / 160, k = j - n * 160;
        v = (k < 147) ? Wib[(size_t)k * 256 + n] : 0.f;
        ph = WibT_hi; pl = WibT_lo; o = j;
    } else if (idx < 278528) {
        int j = idx - 81920;
        int d = j >> 16, rem = j & 65535, n = rem >> 8, k = rem & 255;
        v = Wh[(size_t)d * 65536 + (size_t)k * 256 + n];
        ph = WhT_hi; pl = WhT_lo; o = j;   // layout d*65536 + n*256 + k == j
    } else if (idx < 475136) {
        int j = idx - 278528;
        int n = j / 768, k = j - n * 768;
        v = Wlr[(size_t)k * 256 + n];
        ph = WlrT_hi; pl = WlrT_lo; o = j;
    } else if (idx < 540672) {
        int j = idx - 475136;
        int n = j >> 8, k = j & 255;
        v = Wo[(size_t)k * 256 + n];
        ph = WoT_hi; pl = WoT_lo; o = j;
    } else return;
    unsigned short hb = f2bf_rne(v);
    ph[o] = (short)hb;
    pl[o] = (short)f2bf_rne(v - bfu2f(hb));
}

// ---------------------------------------------------------------------------
// Unified split-bf16 MFMA GEMM (streaming A): 128x256 tile, 512 thr, 8 waves.
// SRC 0: A = fp32 X [M,Kact] (zero-pad to KPAD)       (init GEMMs)
// SRC 1: A = [aggb f32 | matom f32 | iatom bf16], K=768 (cat GEMM)
// SRC 2: A = bf16 X [M,256] (no lo term)              (out GEMM)
// EPI 0: relu->f32  1: relu->bf16  2: relu*MB_SCALE->f16  3: raw->bf16
// EPI 4: relu(x+bias)->f32
// ---------------------------------------------------------------------------
template <int KPAD, int SRC, int EPI>
__global__ __launch_bounds__(512, 4) void mfma_gemm(
    const void* __restrict__ a0, const void* __restrict__ a1,
    const void* __restrict__ a2,
    const short* __restrict__ Bhi, const short* __restrict__ Blo,
    const float* __restrict__ bias, void* __restrict__ outv,
    int M, int Kact)
{
    __shared__ short As_hi[128 * 40];
    __shared__ short As_lo[(SRC == 2) ? 8 : 128 * 40];

    const int tid  = threadIdx.x;
    const int lane = tid & 63;
    const int w    = tid >> 6;          // 0..7
    const int wm   = (w >> 2) * 64;     // {0,64}
    const int wn   = (w & 3) * 64;      // {0,64,128,192}
    const int row0 = blockIdx.x * 128;

    const int sm = tid >> 2;            // staging row 0..127 (4 thr/row)
    const int sk = (tid & 3) * 8;       // staging k-offset 0/8/16/24
    const int fm = lane & 15;
    const int fk = (lane >> 4) * 8;

    int grow = row0 + sm; if (grow > M - 1) grow = M - 1;

    f32x4 acc[4][4];
#pragma unroll
    for (int i = 0; i < 4; ++i)
#pragma unroll
        for (int j = 0; j < 4; ++j) {
            f32x4 z = {0.f, 0.f, 0.f, 0.f};
            acc[i][j] = z;
        }

    for (int k0 = 0; k0 < KPAD; k0 += 32) {
        __syncthreads();
        // ---- stage A tile (pre-split), 8 elems/thread ----
        int base = sm * 40 + sk;
        if (SRC == 0) {
            const float* xrow = (const float*)a0 + (size_t)grow * Kact;
            bh8 h0, l0;
#pragma unroll
            for (int j = 0; j < 8; ++j) {
                int kc = k0 + sk + j;
                float v = (kc < Kact) ? xrow[kc] : 0.f;
                unsigned short hb = f2bf_rne(v);
                h0[j] = (short)hb; l0[j] = (short)f2bf_rne(v - bfu2f(hb));
            }
            *(bh8*)&As_hi[base] = h0;
            *(bh8*)&As_lo[base] = l0;
        } else if (SRC == 1) {
            if (k0 < 512) {
                const float* src = (k0 < 256) ? (const float*)a0 : (const float*)a1;
                int kl = k0 & 255;
                const float4* p = (const float4*)(src + (size_t)grow * 256 + kl + sk);
                float va[8];
#pragma unroll
                for (int q = 0; q < 2; ++q) {
                    float4 f = p[q];
                    va[q * 4 + 0] = f.x; va[q * 4 + 1] = f.y;
                    va[q * 4 + 2] = f.z; va[q * 4 + 3] = f.w;
                }
                bh8 h0, l0;
#pragma unroll
                for (int j = 0; j < 8; ++j) {
                    unsigned short hb = f2bf_rne(va[j]);
                    h0[j] = (short)hb; l0[j] = (short)f2bf_rne(va[j] - bfu2f(hb));
                }
                *(bh8*)&As_hi[base] = h0;
                *(bh8*)&As_lo[base] = l0;
            } else {
                const short* ia = (const short*)a2 + (size_t)grow * 256 + (k0 - 512) + sk;
                bh8 z;
#pragma unroll
                for (int j = 0; j < 8; ++j) z[j] = 0;
                *(bh8*)&As_hi[base] = *(const bh8*)ia;
                *(bh8*)&As_lo[base] = z;
            }
        } else {
            const short* xr = (const short*)a0 + (size_t)grow * 256 + k0 + sk;
            *(bh8*)&As_hi[base] = *(const bh8*)xr;
        }
        __syncthreads();

        // ---- B fragments from pre-split global (L2-resident) ----
        bh8 bhf[4], blf[4];
#pragma unroll
        for (int nt = 0; nt < 4; ++nt) {
            int n = wn + nt * 16 + fm;
            size_t off = (size_t)n * KPAD + k0 + fk;
            bhf[nt] = *(const bh8*)(Bhi + off);
            blf[nt] = *(const bh8*)(Blo + off);
        }
#pragma unroll
        for (int mt = 0; mt < 4; ++mt) {
            int abase = (wm + mt * 16 + fm) * 40 + fk;
            bh8 ah = *(const bh8*)&As_hi[abase];
#pragma unroll
            for (int nt = 0; nt < 4; ++nt) {
                acc[mt][nt] = mfma16(ah, bhf[nt], acc[mt][nt]);
                acc[mt][nt] = mfma16(ah, blf[nt], acc[mt][nt]);
            }
            if (SRC != 2) {
                bh8 al = *(const bh8*)&As_lo[abase];
#pragma unroll
                for (int nt = 0; nt < 4; ++nt)
                    acc[mt][nt] = mfma16(al, bhf[nt], acc[mt][nt]);
            }
        }
    }

    // ---- epilogue (C layout: col=lane&15, row=(lane>>4)*4+r) ----
#pragma unroll
    for (int mt = 0; mt < 4; ++mt) {
        int rbase = row0 + wm + mt * 16 + (lane >> 4) * 4;
#pragma unroll
        for (int nt = 0; nt < 4; ++nt) {
            int col = wn + nt * 16 + fm;
            float bc = (EPI == 4) ? bias[col] : 0.f;
#pragma unroll
            for (int r = 0; r < 4; ++r) {
                int row = rbase + r;
                if (row < M) {
                    size_t o = (size_t)row * 256 + col;
                    float v = acc[mt][nt][r];
                    if (EPI == 0)      ((float*)outv)[o] = fmaxf(v, 0.f);
                    else if (EPI == 1) ((unsigned short*)outv)[o] = f2bf_rne(fmaxf(v, 0.f));
                    else if (EPI == 2) ((f16*)outv)[o] = (f16)(fmaxf(v, 0.f) * MB_SCALE);
                    else if (EPI == 3) ((unsigned short*)outv)[o] = f2bf_rne(v);
                    else               ((float*)outv)[o] = fmaxf(v + bc, 0.f);
                }
            }
        }
    }
}

// ---------------------------------------------------------------------------
// Bond update via split-bf16 MFMA, 2-deep gather pipeline (spill-proofed):
//   WITH_FB=1: mb_new = relu( relu(FB@Wib) + (matom[b2a] - 4096*mb[b2revb])@Wh ) * 2^-12
//   WITH_FB=0: mb_new = relu( 4096*ib     + (matom[b2a] - 4096*mb[b2revb])@Wh ) * 2^-12
// 128x256 tile, 512 thr, dbuf LDS (stride 44: conflict-free), 1 barrier/step.
// Steps s=0..4 phase1 (Wib, WITH_FB only), s=5..12 phase2 (Wh). FULLY
// UNROLLED: buf index, raw-set parity, phase all compile-time. Raw prefetch
// for step s+2 issued at step s (2 compute phases of latency cover) into
// named register sets (x*/y*, parity s&1). B-frags in 2 groups of 2 cols
// (live 16 regs). ib/mb_new may alias (d1 in-place): no __restrict__.
// ---------------------------------------------------------------------------
#define BOND_ISSUE_G(A0, A1, RR, t) {                                        \
    int kb_ = ((t) - 5) * 32 + sk;                                           \
    A0 = *(const float4*)(arow + kb_);                                       \
    A1 = *(const float4*)(arow + kb_ + 4);                                   \
    RR = *(const f16x8*)(rrow + kb_);                                        \
}
#define BOND_ISSUE_F(A0, A1, t) {                                            \
    int kb_ = (t) * 32 + sk;                                                 \
    float t0_ = (kb_ + 0 < 147) ? frow[kb_ + 0] : 0.f;                       \
    float t1_ = (kb_ + 1 < 147) ? frow[kb_ + 1] : 0.f;                       \
    float t2_ = (kb_ + 2 < 147) ? frow[kb_ + 2] : 0.f;                       \
    float t3_ = (kb_ + 3 < 147) ? frow[kb_ + 3] : 0.f;                       \
    float t4_ = (kb_ + 4 < 147) ? frow[kb_ + 4] : 0.f;                       \
    float t5_ = (kb_ + 5 < 147) ? frow[kb_ + 5] : 0.f;                       \
    float t6_ = (kb_ + 6 < 147) ? frow[kb_ + 6] : 0.f;                       \
    float t7_ = (kb_ + 7 < 147) ? frow[kb_ + 7] : 0.f;                       \
    A0 = make_float4(t0_, t1_, t2_, t3_);                                    \
    A1 = make_float4(t4_, t5_, t6_, t7_);                                    \
}
#define BOND_SPLIT8(V0,V1,V2,V3,V4,V5,V6,V7, buf) {                          \
    bh8 h_, l_;                                                              \
    unsigned short hb_;                                                      \
    hb_ = f2bf_rne(V0); h_[0] = (short)hb_; l_[0] = (short)f2bf_rne(V0 - bfu2f(hb_)); \
    hb_ = f2bf_rne(V1); h_[1] = (short)hb_; l_[1] = (short)f2bf_rne(V1 - bfu2f(hb_)); \
    hb_ = f2bf_rne(V2); h_[2] = (short)hb_; l_[2] = (short)f2bf_rne(V2 - bfu2f(hb_)); \
    hb_ = f2bf_rne(V3); h_[3] = (short)hb_; l_[3] = (short)f2bf_rne(V3 - bfu2f(hb_)); \
    hb_ = f2bf_rne(V4); h_[4] = (short)hb_; l_[4] = (short)f2bf_rne(V4 - bfu2f(hb_)); \
    hb_ = f2bf_rne(V5); h_[5] = (short)hb_; l_[5] = (short)f2bf_rne(V5 - bfu2f(hb_)); \
    hb_ = f2bf_rne(V6); h_[6] = (short)hb_; l_[6] = (short)f2bf_rne(V6 - bfu2f(hb_)); \
    hb_ = f2bf_rne(V7); h_[7] = (short)hb_; l_[7] = (short)f2bf_rne(V7 - bfu2f(hb_)); \
    *(bh8*)&As[buf][0][lbase] = h_;                                          \
    *(bh8*)&As[buf][1][lbase] = l_;                                          \
}
#define BOND_STORE_G(A0, A1, RR, buf) {                                      \
    float v0_ = fmaf(-MB_INV, (float)RR[0], A0.x);                           \
    float v1_ = fmaf(-MB_INV, (float)RR[1], A0.y);                           \
    float v2_ = fmaf(-MB_INV, (float)RR[2], A0.z);                           \
    float v3_ = fmaf(-MB_INV, (float)RR[3], A0.w);                           \
    float v4_ = fmaf(-MB_INV, (float)RR[4], A1.x);                           \
    float v5_ = fmaf(-MB_INV, (float)RR[5], A1.y);                           \
    float v6_ = fmaf(-MB_INV, (float)RR[6], A1.z);                           \
    float v7_ = fmaf(-MB_INV, (float)RR[7], A1.w);                           \
    BOND_SPLIT8(v0_, v1_, v2_, v3_, v4_, v5_, v6_, v7_, buf)                 \
}
#define BOND_STORE_F(A0, A1, buf) {                                          \
    BOND_SPLIT8(A0.x, A0.y, A0.z, A0.w, A1.x, A1.y, A1.z, A1.w, buf)         \
}
// compute one k-step from LDS buf; B in 2 groups of 2 cols (live 16 regs)
#define BOND_COMPUTE(buf, Bh, Bl, ldb, k0) {                                 \
    _Pragma("unroll")                                                        \
    for (int g_ = 0; g_ < 2; ++g_) {                                         \
        size_t o0_ = (size_t)(wn + (g_ * 2 + 0) * 16 + fm) * (ldb) + (k0) + fk; \
        size_t o1_ = (size_t)(wn + (g_ * 2 + 1) * 16 + fm) * (ldb) + (k0) + fk; \
        bh8 b0h_ = *(const bh8*)((Bh) + o0_);                                \
        bh8 b0l_ = *(const bh8*)((Bl) + o0_);                                \
        bh8 b1h_ = *(const bh8*)((Bh) + o1_);                                \
        bh8 b1l_ = *(const bh8*)((Bl) + o1_);                                \
        _Pragma("unroll")                                                    \
        for (int mt_ = 0; mt_ < 4; ++mt_) {                                  \
            int ab_ = (wm + mt_ * 16 + fm) * 44 + fk;                        \
            bh8 ah_ = *(const bh8*)&As[buf][0][ab_];                         \
            bh8 al_ = *(const bh8*)&As[buf][1][ab_];                         \
            acc[mt_][g_ * 2 + 0] = mfma16(ah_, b0h_, acc[mt_][g_ * 2 + 0]);  \
            acc[mt_][g_ * 2 + 0] = mfma16(ah_, b0l_, acc[mt_][g_ * 2 + 0]);  \
            acc[mt_][g_ * 2 + 0] = mfma16(al_, b0h_, acc[mt_][g_ * 2 + 0]);  \
            acc[mt_][g_ * 2 + 1] = mfma16(ah_, b1h_, acc[mt_][g_ * 2 + 1]);  \
            acc[mt_][g_ * 2 + 1] = mfma16(ah_, b1l_, acc[mt_][g_ * 2 + 1]);  \
            acc[mt_][g_ * 2 + 1] = mfma16(al_, b1h_, acc[mt_][g_ * 2 + 1]);  \
        }                                                                    \
    }                                                                        \
}

template <bool WITH_FB>
__global__ __launch_bounds__(512, 4) void bond_mfma_kernel(
    const float* __restrict__ FB,
    const short* __restrict__ WibT_hi, const short* __restrict__ WibT_lo,
    const short* __restrict__ WhT_hi,  const short* __restrict__ WhT_lo,
    const float* __restrict__ matom, const f16* __restrict__ mb_old,
    const f16* ib,
    const int* __restrict__ b2a, const int* __restrict__ b2revb,
    f16* mb_new, int M)
{
    __shared__ short As[2][2][128 * 44];   // [buf][hi|lo], stride 44: no conflicts

    const int tid  = threadIdx.x;
    const int lane = tid & 63;
    const int w    = tid >> 6;
    const int wm   = (w >> 2) * 64;
    const int wn   = (w & 3) * 64;
    const int row0 = blockIdx.x * 128;

    const int sm = tid >> 2;            // 0..127
    const int sk = (tid & 3) * 8;       // 0/8/16/24
    const int lbase = sm * 44 + sk;     // LDS staging offset (shorts)

    int grow = row0 + sm; if (grow > M - 1) grow = M - 1;
    const float* frow = FB + (size_t)grow * 147;
    const float* arow = matom + (size_t)b2a[grow] * 256;
    const f16*   rrow = mb_old + (size_t)b2revb[grow] * 256;

    const int fm = lane & 15;
    const int fk = (lane >> 4) * 8;

    f32x4 acc[4][4];
#pragma unroll
    for (int i = 0; i < 4; ++i)
#pragma unroll
        for (int j = 0; j < 4; ++j) {
            f32x4 z = {0.f, 0.f, 0.f, 0.f};
            acc[i][j] = z;
        }

    // two named raw-capture sets, alternating by absolute step parity
    float4 xa0, xa1; f16x8 xr;   // even steps
    float4 ya0, ya1; f16x8 yr;   // odd steps

    const int S0 = WITH_FB ? 0 : 5;

    // ---- prologue: stage step S0 into buf0; issue raw(S0+1) ----
    if (WITH_FB) {
        BOND_ISSUE_F(xa0, xa1, 0)              // step 0 (even -> x)
        BOND_STORE_F(xa0, xa1, 0)
        BOND_ISSUE_F(ya0, ya1, 1)              // step 1 (odd -> y)
    } else {
        BOND_ISSUE_G(ya0, ya1, yr, 5)          // step 5 (odd -> y)
        BOND_STORE_G(ya0, ya1, yr, 0)
        BOND_ISSUE_G(xa0, xa1, xr, 6)          // step 6 (even -> x)
    }
    __syncthreads();

    // ---- fully static main loop ----
#pragma unroll
    for (int s = S0; s <= 12; ++s) {
        const int buf = (s - S0) & 1;
        // issue raw for step s+2 into set (s+2)&1 == s&1
        if (s + 2 <= 12) {
            if ((s & 1) == 0) {
                if (WITH_FB && (s + 2) < 5) { BOND_ISSUE_F(xa0, xa1, s + 2) }
                else                        { BOND_ISSUE_G(xa0, xa1, xr, s + 2) }
            } else {
                if (WITH_FB && (s + 2) < 5) { BOND_ISSUE_F(ya0, ya1, s + 2) }
                else                        { BOND_ISSUE_G(ya0, ya1, yr, s + 2) }
            }
        }
        // compute step s from LDS buf
        if (WITH_FB && s < 5) {
            BOND_COMPUTE(buf, WibT_hi, WibT_lo, 160, s * 32)
        } else {
            BOND_COMPUTE(buf, WhT_hi, WhT_lo, 256, (s - 5) * 32)
        }
        if (WITH_FB && s == 4) {
#pragma unroll
            for (int i = 0; i < 4; ++i)
#pragma unroll
                for (int j = 0; j < 4; ++j)
#pragma unroll
                    for (int r = 0; r < 4; ++r)
                        acc[i][j][r] = fmaxf(acc[i][j][r], 0.f);
        }
        // store raw(s+1) (set (s+1)&1) into buf^1
        if (s < 12) {
            if (((s + 1) & 1) == 0) {
                if (WITH_FB && (s + 1) < 5) { BOND_STORE_F(xa0, xa1, buf ^ 1) }
                else                        { BOND_STORE_G(xa0, xa1, xr, buf ^ 1) }
            } else {
                if (WITH_FB && (s + 1) < 5) { BOND_STORE_F(ya0, ya1, buf ^ 1) }
                else                        { BOND_STORE_G(ya0, ya1, yr, buf ^ 1) }
            }
            __syncthreads();
        }
    }

#pragma unroll
    for (int mt = 0; mt < 4; ++mt) {
        int rbase = row0 + wm + mt * 16 + (lane >> 4) * 4;
#pragma unroll
        for (int nt = 0; nt < 4; ++nt) {
            int col = wn + nt * 16 + fm;
#pragma unroll
            for (int r = 0; r < 4; ++r) {
                int row = rbase + r;
                if (row < M) {
                    size_t o = (size_t)row * 256 + col;
                    float v = acc[mt][nt][r];
                    if (!WITH_FB) v = fmaf(MB_INV, (float)ib[o], v);
                    mb_new[o] = (f16)(fmaxf(v, 0.f) * MB_SCALE);
                }
            }
        }
    }
}

// agg = sum_j(mb[a2b[a,j]]) * max_j(mb[a2b[a,j]]) per channel, true scale.
// 4 atoms/block, 64 lanes/atom, f16x4 (8B/lane) gather loads.
__global__ __launch_bounds__(256) void agg_kernel(
    const f16* __restrict__ mb, const int* __restrict__ a2b,
    float* __restrict__ matom, float* __restrict__ agg_out, int A)
{
    const int a    = blockIdx.x * 4 + (threadIdx.x >> 6);
    const int lane = threadIdx.x & 63;
    if (a >= A) return;
    const int* nb = a2b + (size_t)a * 6;

    f16x4 v0 = *(const f16x4*)(mb + (size_t)nb[0] * 256 + lane * 4);
    float s0 = (float)v0[0], s1 = (float)v0[1], s2 = (float)v0[2], s3 = (float)v0[3];
    float m0 = s0, m1 = s1, m2 = s2, m3 = s3;
#pragma unroll
    for (int j = 1; j < 6; ++j) {
        f16x4 v = *(const f16x4*)(mb + (size_t)nb[j] * 256 + lane * 4);
        float f0 = (float)v[0], f1 = (float)v[1], f2 = (float)v[2], f3 = (float)v[3];
        s0 += f0; s1 += f1; s2 += f2; s3 += f3;
        m0 = fmaxf(m0, f0); m1 = fmaxf(m1, f1);
        m2 = fmaxf(m2, f2); m3 = fmaxf(m3, f3);
    }
    size_t o = (size_t)a * 256 + lane * 4;
    if (agg_out) {
        float4 g = { AGG_INV * s0 * m0, AGG_INV * s1 * m1,
                     AGG_INV * s2 * m2, AGG_INV * s3 * m3 };
        *(float4*)(agg_out + o) = g;
    } else {
        float4 m = *(const float4*)(matom + o);
        m.x += AGG_INV * s0 * m0; m.y += AGG_INV * s1 * m1;
        m.z += AGG_INV * s2 * m2; m.w += AGG_INV * s3 * m3;
        *(float4*)(matom + o) = m;
    }
}

// Exclusive prefix sum of sizes -> offsets (one block, M=5000). Raw, unclipped.
__global__ __launch_bounds__(256) void scan_kernel(
    const int* __restrict__ sizes, int* __restrict__ offsets, int M)
{
    __shared__ int part[256];
    const int t = threadIdx.x;
    const int chunk = (M + 255) / 256;
    int begin = t * chunk;
    int end = begin + chunk; if (end > M) end = M;
    int s = 0;
    for (int i = begin; i < end && i < M; ++i) s += sizes[i];
    part[t] = s;
    __syncthreads();
    for (int off = 1; off < 256; off <<= 1) {
        int v = (t >= off) ? part[t - off] : 0;
        __syncthreads();
        part[t] += v;
        __syncthreads();
    }
    int run = part[t] - s;
    for (int i = begin; i < end && i < M; ++i) { offsets[i] = run; run += sizes[i]; }
}

// Per-molecule mean pooling with jnp.repeat(total_repeat_length=A) DROP
// semantics (sizes[M-1] may be negative).
__global__ __launch_bounds__(256) void pool_kernel(
    const float* __restrict__ hid, const int* __restrict__ offsets,
    const int* __restrict__ sizes, float* __restrict__ out, int M, int A)
{
    const int m = blockIdx.x;
    const int h = threadIdx.x;
    int e = offsets[m];
    int sz = sizes[m];
    int start = e < A ? e : A;          if (start < 0) start = 0;
    int stop  = e + sz; if (stop > A) stop = A; if (stop < 0) stop = 0;
    float s = 0.f;
    for (int i = start; i < stop; ++i)
        s += hid[(size_t)i * 256 + h];
    out[(size_t)m * 256 + h] = s / (float)sz;
}

extern "C" void kernel_launch(void* const* d_in, const int* in_sizes, int n_in,
                              void* d_out, int out_size, void* d_ws, size_t ws_size,
                              hipStream_t stream)
{
    const float* f_atoms = (const float*)d_in[0];
    const float* f_bonds = (const float*)d_in[1];
    const float* W_ia    = (const float*)d_in[2];
    const float* W_ib    = (const float*)d_in[3];
    const float* W_h     = (const float*)d_in[4];
    const float* W_o     = (const float*)d_in[5];
    const float* b_o     = (const float*)d_in[6];
    const float* W_lr    = (const float*)d_in[7];
    const int*   a2b     = (const int*)d_in[8];
    const int*   b2a     = (const int*)d_in[9];
    const int*   b2revb  = (const int*)d_in[10];
    const int*   sizes   = (const int*)d_in[11];
    float* out = (float*)d_out;   // fp32 [5000,256]

    const int An = 100000, Bn = 200000, Mm = 5000;
    const size_t ABYTES = (size_t)An * 256 * 4;   // 102,400,000
    const size_t BBYTES = (size_t)Bn * 256 * 2;   // 102,400,000 (fp16)

    int*   offsets = (int*)d_ws;                                  // 32 KB
    float* matom   = (float*)((char*)d_ws + 32768);               // fp32 [A,256]
    f16*   mb0     = (f16*)((char*)matom + ABYTES);
    f16*   mb1     = (f16*)((char*)mb0 + BBYTES);
    short* wsplit  = (short*)((char*)mb1 + BBYTES);               // 51.2 MB tail
    // total footprint unchanged: 358,432,768 B (proven safe)

    short* WiaT_hi = wsplit;
    short* WiaT_lo = wsplit + 40960;
    short* WibT_hi = wsplit + 81920;
    short* WibT_lo = wsplit + 122880;
    short* WhT_hi  = wsplit + 163840;
    short* WhT_lo  = wsplit + 360448;
    short* WlrT_hi = wsplit + 557056;
    short* WlrT_lo = wsplit + 753664;
    short* WoT_hi  = wsplit + 950272;
    short* WoT_lo  = wsplit + 1015808;

    dim3 blk(256);
    dim3 blk512(512);
    dim3 gA((An + 127) / 128, 1);    // 782
    dim3 gB((Bn + 127) / 128, 1);    // 1563

    wprep_kernel<<<2112, blk, 0, stream>>>(W_ia, W_ib, W_h, W_lr, W_o, wsplit);

    // input projections (split-MFMA)
    mfma_gemm<160, 0, 0><<<gA, blk512, 0, stream>>>(
        f_atoms, nullptr, nullptr, WiaT_hi, WiaT_lo, nullptr, matom, An, 133);
    mfma_gemm<160, 0, 2><<<gB, blk512, 0, stream>>>(
        f_bonds, nullptr, nullptr, WibT_hi, WibT_lo, nullptr, mb0, Bn, 147);

    // message passing (3 iterations); ib == initial mb0, reused by iters 0,1
    // d0: agg(mb0); fast(old=mb0, ib=mb0) -> mb1
    agg_kernel<<<(An + 3) / 4, blk, 0, stream>>>(mb0, a2b, matom, (float*)nullptr, An);
    bond_mfma_kernel<false><<<gB, blk512, 0, stream>>>(
        f_bonds, WibT_hi, WibT_lo, WhT_hi, WhT_lo,
        matom, mb0, mb0, b2a, b2revb, mb1, Bn);
    // d1: agg(mb1); fast(old=mb1, ib=mb0) -> mb0 IN-PLACE over ib (race-free:
    //     each thread reads ib[o] then writes mb_new[o] at the same o; gather
    //     source is mb1)
    agg_kernel<<<(An + 3) / 4, blk, 0, stream>>>(mb1, a2b, matom, (float*)nullptr, An);
    bond_mfma_kernel<false><<<gB, blk512, 0, stream>>>(
        f_bonds, WibT_hi, WibT_lo, WhT_hi + 65536, WhT_lo + 65536,
        matom, mb1, mb0, b2a, b2revb, mb0, Bn);
    // d2: agg(mb0); slow (recompute FB@Wib; ib destroyed) -> mb1
    agg_kernel<<<(An + 3) / 4, blk, 0, stream>>>(mb0, a2b, matom, (float*)nullptr, An);
    bond_mfma_kernel<true><<<gB, blk512, 0, stream>>>(
        f_bonds, WibT_hi, WibT_lo, WhT_hi + 131072, WhT_lo + 131072,
        matom, mb0, nullptr, b2a, b2revb, mb1, Bn);
    // final message_bond = mb1 (same as before)

    float* aggbuf = (float*)mb0;                       // fp32 [A,256]
    agg_kernel<<<(An + 3) / 4, blk, 0, stream>>>(mb1, a2b, matom, aggbuf, An);

    // iatom bf16 -> first half of (now dead) mb1; t1 bf16 -> second half
    unsigned short* iatom = (unsigned short*)mb1;
    unsigned short* t1    = (unsigned short*)((char*)mb1 + 51200000);
    mfma_gemm<160, 0, 1><<<gA, blk512, 0, stream>>>(
        f_atoms, nullptr, nullptr, WiaT_hi, WiaT_lo, nullptr, iatom, An, 133);

    mfma_gemm<768, 1, 3><<<gA, blk512, 0, stream>>>(
        aggbuf, matom, iatom, WlrT_hi, WlrT_lo, nullptr, t1, An, 768);

    float* hid = (float*)mb0;                          // aggbuf dead after cat
    mfma_gemm<256, 2, 4><<<gA, blk512, 0, stream>>>(
        t1, nullptr, nullptr, WoT_hi, WoT_lo, b_o, hid, An, 256);

    scan_kernel<<<1, 256, 0, stream>>>(sizes, offsets, Mm);
    pool_kernel<<<Mm, blk, 0, stream>>>(hid, offsets, sizes, out, Mm, An);
}